// Round 8
// baseline (215.095 us; speedup 1.0000x reference)
//
#include <hip/hip_runtime.h>

// ---- problem constants ----
#define D_   1024
#define H_   16
#define T_   2048
#define B_   2
#define BT_  (B_*T_)       // 4096
#define NIN_ 3088          // 3D + H
#define NP_  3200          // padded to 25*128
#define CHUNK_ 64
#define NCH_  (T_/CHUNK_)  // 32 chunks
#define GN_INV (1.0f/131072.0f)  // 1/(K*T)
#define NBLK_C (BT_ * D_ / 256)  // 16384 applyC blocks

typedef unsigned short u16;
typedef __attribute__((ext_vector_type(8))) __bf16 bf16x8;
typedef __attribute__((ext_vector_type(4))) float  f32x4;

struct __align__(16) F4 { float x, y, z, w; };
struct __align__(8)  U4 { u16 x, y, z, w; };

__device__ inline u16 f2bf(float f) {
  union { float f; unsigned u; } q; q.f = f;
  unsigned r = q.u + 0x7FFFu + ((q.u >> 16) & 1u);   // RNE
  return (u16)(r >> 16);
}
__device__ inline float bf2f(u16 v) {
  union { unsigned u; float f; } q; q.u = ((unsigned)v) << 16; return q.f;
}

__device__ inline void gl_lds16(const void* g, void* l) {
  __builtin_amdgcn_global_load_lds(
      (const __attribute__((address_space(1))) unsigned*)g,
      (__attribute__((address_space(3))) unsigned*)l, 16, 0, 0);
}

// ---------------- fused f32 -> bf16 converts (x, W_in padded, W_out) ----------------
__global__ void cvt_all(const float* __restrict__ x, const float* __restrict__ W_in,
                        const float* __restrict__ W_out,
                        u16* __restrict__ xb, u16* __restrict__ wb, u16* __restrict__ wob) {
  const int nx = BT_ * D_ / 4, nw = NP_ * D_ / 4, no = D_ * D_ / 4;
  int q = blockIdx.x * 256 + threadIdx.x;
  if (q < nx) {
    int i = q * 4;
    F4 f = *reinterpret_cast<const F4*>(x + i);
    U4 u; u.x = f2bf(f.x); u.y = f2bf(f.y); u.z = f2bf(f.z); u.w = f2bf(f.w);
    *reinterpret_cast<U4*>(xb + i) = u;
  } else if (q < nx + nw) {
    int i = (q - nx) * 4;
    int row = i >> 10;
    U4 u; u.x = 0; u.y = 0; u.z = 0; u.w = 0;
    if (row < NIN_) {
      F4 f = *reinterpret_cast<const F4*>(W_in + i);
      u.x = f2bf(f.x); u.y = f2bf(f.y); u.z = f2bf(f.z); u.w = f2bf(f.w);
    }
    *reinterpret_cast<U4*>(wb + i) = u;
  } else if (q < nx + nw + no) {
    int i = (q - nx - nw) * 4;
    F4 f = *reinterpret_cast<const F4*>(W_out + i);
    U4 u; u.x = f2bf(f.x); u.y = f2bf(f.y); u.z = f2bf(f.z); u.w = f2bf(f.w);
    *reinterpret_cast<U4*>(wob + i) = u;
  }
}

// ---------------- bf16 GEMM: C[M,N] = A[M,K] * B[N,K]^T ----------------
// 128x128 tile, BK=64, 4 waves (2x2 of 64x64), mfma_f32_16x16x32_bf16.
// LDS XOR-swizzle (rule 21): linear LDS dest for global_load_lds, source
// 16B-block pre-permuted by blk^(row&7); ds_read applies the same XOR.
// BF16OUT: write C as bf16 (GEMM1->proj), else f32 (GEMM2->d_out).
template<bool BF16OUT>
__global__ __launch_bounds__(256, 2) void gemm_bt(
    const u16* __restrict__ A, const u16* __restrict__ Bm,
    void* __restrict__ Cv, int M, int N, int K) {
  __shared__ __align__(16) u16 As[128 * 64];
  __shared__ __align__(16) u16 Bs[128 * 64];
  const int tid  = threadIdx.x;
  const int lane = tid & 63;
  const int wid  = tid >> 6;
  const int tm = blockIdx.y * 128, tn = blockIdx.x * 128;
  const int wm = (wid >> 1) * 64,  wn = (wid & 1) * 64;
  const int krow = lane & 15;
  const int ksub = (lane >> 4) * 8;
  f32x4 acc[4][4] = {};

  for (int kt = 0; kt < K; kt += 64) {
#pragma unroll
    for (int i = 0; i < 4; ++i) {
      int e = i * 2048 + tid * 8;          // element idx in [128][64] tile
      int r = e >> 6;
      int c = (((tid & 7) ^ (r & 7)) << 3); // pre-swizzled source column
      gl_lds16(A  + (size_t)(tm + r) * K + kt + c, &As[e]);
      gl_lds16(Bm + (size_t)(tn + r) * K + kt + c, &Bs[e]);
    }
    __syncthreads();                        // drains vmcnt before ds_read
#pragma unroll
    for (int kk = 0; kk < 64; kk += 32) {
      bf16x8 af[4], bfr[4];
#pragma unroll
      for (int i = 0; i < 4; ++i) {
        int row = wm + i * 16 + krow;
        int b = (((kk + ksub) >> 3) ^ (row & 7)) << 3;
        af[i] = *reinterpret_cast<const bf16x8*>(&As[row * 64 + b]);
      }
#pragma unroll
      for (int i = 0; i < 4; ++i) {
        int row = wn + i * 16 + krow;
        int b = (((kk + ksub) >> 3) ^ (row & 7)) << 3;
        bfr[i] = *reinterpret_cast<const bf16x8*>(&Bs[row * 64 + b]);
      }
#pragma unroll
      for (int mi = 0; mi < 4; ++mi)
#pragma unroll
        for (int ni = 0; ni < 4; ++ni)
          acc[mi][ni] = __builtin_amdgcn_mfma_f32_16x16x32_bf16(af[mi], bfr[ni], acc[mi][ni], 0, 0, 0);
    }
    __syncthreads();
  }
  // C/D layout (m89-verified): col = lane&15, row = (lane>>4)*4 + j
  const int rb = tm + wm + (lane >> 4) * 4;
  const int cb = tn + wn + (lane & 15);
#pragma unroll
  for (int mi = 0; mi < 4; ++mi)
#pragma unroll
    for (int ni = 0; ni < 4; ++ni)
#pragma unroll
      for (int j = 0; j < 4; ++j) {
        size_t off = (size_t)(rb + mi * 16 + j) * N + cb + ni * 16;
        if constexpr (BF16OUT) ((u16*)Cv)[off] = f2bf(acc[mi][ni][j]);
        else                   ((float*)Cv)[off] = acc[mi][ni][j];
      }
}

// ---------------- fused conv+silu+decay + chunk-local scan ----------------
// grid: (b,h,c) = 2*16*32 blocks of 64 threads (one k each).
// proj (bf16) layout [BT][3200]: r[0,1024) v[1024,2048) k[2048,3072) w[3072,3088)
// Computes gated v on the fly, scans within chunk, emits:
//   vv    = chunk-local scan result y
//   pfx   = running decay prefix exp(cs[t]-cs[t0-1])
//   ye/Pc = chunk summary for cross-chunk combine
__global__ void scanA_kernel(const u16* __restrict__ proj,
                             const float* __restrict__ conv_w,
                             const float* __restrict__ conv_b,
                             const float* __restrict__ decay,
                             float* __restrict__ vv,
                             float* __restrict__ ye, float* __restrict__ Pc,
                             float* __restrict__ pfx) {
  int bh = blockIdx.x >> 5, c = blockIdx.x & 31;
  int b = bh >> 4, h = bh & 15;
  int k = threadIdx.x;                 // 64 lanes
  int d = h * 64 + k;
  int t0 = c * CHUNK_;
  // lane L holds decay factor a for t = t0+L
  float wv = bf2f(proj[(size_t)(b * T_ + t0 + k) * NP_ + 3072 + h]);
  float gte = 1.f / (1.f + __expf(-(decay[h] + wv)));
  float my_a = __expf(-8.f * (1.f - gte) - 0.1f);
  float cw0 = conv_w[d * 4], cw1 = conv_w[d * 4 + 1],
        cw2 = conv_w[d * 4 + 2], cw3 = conv_w[d * 4 + 3];
  float cb = conv_b[d];
  float* V = vv + ((size_t)bh * T_ + t0) * 64 + k;
  float y = 0.f, pf = 1.f, my_pf = 1.f;
#pragma unroll 8
  for (int i = 0; i < CHUNK_; ++i) {
    int t = t0 + i;
    const u16* prow = proj + (size_t)(b * T_ + t) * NP_;
    float v = bf2f(prow[1024 + d]);
    float kc = cb;                     // taps t-6 .. t-3 (k-column, same batch)
    if (t >= 6)      kc = fmaf(bf2f(prow[2048 + d - 6 * NP_]), cw0, kc);
    if (t >= 5)      kc = fmaf(bf2f(prow[2048 + d - 5 * NP_]), cw1, kc);
    if (t >= 4)      kc = fmaf(bf2f(prow[2048 + d - 4 * NP_]), cw2, kc);
    if (t >= 3)      kc = fmaf(bf2f(prow[2048 + d - 3 * NP_]), cw3, kc);
    float sil = kc / (1.f + __expf(-kc));
    float g = v * sil * (1.f / 32.f);
    float a = __shfl(my_a, i);
    y = fmaf(a, y, g);                 // y = g + a*y_prev
    V[(size_t)i * 64] = y;
    pf *= a;
    if (i == k) my_pf = pf;
  }
  pfx[(size_t)bh * T_ + t0 + k] = my_pf;
  ye[(size_t)blockIdx.x * 64 + k] = y;
  Pc[(size_t)blockIdx.x * 64 + k] = pf;
}

// ---------------- cross-chunk combine (tiny) ----------------
__global__ void comb_kernel(const float* __restrict__ ye, const float* __restrict__ Pc,
                            float* __restrict__ cin) {
  int g = blockIdx.x * 256 + threadIdx.x;      // 2048 = (b,h,k)
  int bh = g >> 6, k = g & 63;
  float s = 0.f;
  for (int c = 0; c < NCH_; ++c) {
    size_t i = ((size_t)bh * NCH_ + c) * 64 + k;
    cin[i] = s;
    s = ye[i] + Pc[i] * s;
  }
}

// ---------------- phase C: add carry, out = silu(r)*y, GN partials (no atomics) ----------------
__global__ void applyC_kernel(float* __restrict__ y, const u16* __restrict__ proj,
                              const float* __restrict__ pfx, const float* __restrict__ cin,
                              float* __restrict__ part) {
  int idx = blockIdx.x * 256 + threadIdx.x;    // (bh,t,k) linear
  int k  = idx & 63;
  int t  = (idx >> 6) & 2047;
  int bh = idx >> 17;                          // 256 threads share one bh
  int b = bh >> 4, h = bh & 15;
  float ci = cin[(((size_t)bh * NCH_) + (t >> 6)) * 64 + k];
  float yf = fmaf(pfx[(size_t)bh * T_ + t], ci, y[idx]);
  float r = bf2f(proj[(size_t)(b * T_ + t) * NP_ + h * 64 + k]);
  float o = yf * (r / (1.f + __expf(-r)));
  y[idx] = o;
  // block reduce sum / sumsq -> contention-free per-block partials
  float s1 = o, s2 = o * o;
#pragma unroll
  for (int m = 32; m; m >>= 1) { s1 += __shfl_xor(s1, m); s2 += __shfl_xor(s2, m); }
  __shared__ float ps[8];
  int wid = threadIdx.x >> 6, lane = threadIdx.x & 63;
  if (lane == 0) { ps[wid] = s1; ps[4 + wid] = s2; }
  __syncthreads();
  if (threadIdx.x == 0) {
    part[blockIdx.x]          = ps[0] + ps[1] + ps[2] + ps[3];
    part[NBLK_C + blockIdx.x] = ps[4] + ps[5] + ps[6] + ps[7];
  }
}

// ---------------- reduce partials -> sums[bh], sums[32+bh] ----------------
// applyC block b has bh = b>>9 (512 blocks per bh, contiguous)
__global__ void reduce_kernel(const float* __restrict__ part, float* __restrict__ sums) {
  int bh = blockIdx.x;                         // 32 blocks, 256 threads
  int t = threadIdx.x;
  int base = bh * 512;
  float s1 = part[base + t]           + part[base + 256 + t];
  float s2 = part[NBLK_C + base + t]  + part[NBLK_C + base + 256 + t];
#pragma unroll
  for (int m = 32; m; m >>= 1) { s1 += __shfl_xor(s1, m); s2 += __shfl_xor(s2, m); }
  __shared__ float ps[8];
  int wid = t >> 6, lane = t & 63;
  if (lane == 0) { ps[wid] = s1; ps[4 + wid] = s2; }
  __syncthreads();
  if (t == 0) {
    sums[bh]      = ps[0] + ps[1] + ps[2] + ps[3];
    sums[32 + bh] = ps[4] + ps[5] + ps[6] + ps[7];
  }
}

// ---------------- phase D: normalize + bf16 cast to (b,t,d) ----------------
__global__ void applyD_kernel(const float* __restrict__ o, const float* __restrict__ sums,
                              const float* __restrict__ gn_w, const float* __restrict__ gn_b,
                              u16* __restrict__ on) {
  int idx = blockIdx.x * 256 + threadIdx.x;    // (bh,t,k) linear
  int k  = idx & 63;
  int t  = (idx >> 6) & 2047;
  int bh = idx >> 17;
  int b = bh >> 4, h = bh & 15;
  float mean = sums[bh] * GN_INV;
  float var  = sums[32 + bh] * GN_INV - mean * mean;
  float inv  = rsqrtf(var + 1e-5f);
  int d = h * 64 + k;
  float val = (o[idx] - mean) * inv * gn_w[d] + gn_b[d];
  on[(size_t)(b * T_ + t) * D_ + d] = f2bf(val);
}

// ---------------- launch ----------------
extern "C" void kernel_launch(void* const* d_in, const int* in_sizes, int n_in,
                              void* d_out, int out_size, void* d_ws, size_t ws_size,
                              hipStream_t stream) {
  const float* x      = (const float*)d_in[0];
  const float* W_in   = (const float*)d_in[1];
  const float* conv_w = (const float*)d_in[2];
  const float* conv_b = (const float*)d_in[3];
  const float* decay  = (const float*)d_in[4];
  const float* gn_w   = (const float*)d_in[5];
  const float* gn_b   = (const float*)d_in[6];
  const float* W_out  = (const float*)d_in[7];

  char* p = (char*)d_ws;
  auto alloc = [&](size_t bytes) { void* r = (void*)p; p += (bytes + 255) & ~(size_t)255; return r; };
  u16*  xb   = (u16*)alloc((size_t)BT_ * D_ * 2);   // also reused as `on` after GEMM1
  u16*  wb   = (u16*)alloc((size_t)NP_ * D_ * 2);
  u16*  wob  = (u16*)alloc((size_t)D_ * D_ * 2);
  u16*  proj = (u16*)alloc((size_t)BT_ * NP_ * 2);  // bf16 proj
  float* vv   = (float*)alloc((size_t)BT_ * D_ * 4);
  float* pfx  = (float*)alloc((size_t)B_ * H_ * T_ * 4);
  float* ye   = (float*)alloc((size_t)B_ * H_ * NCH_ * 64 * 4);
  float* Pc   = (float*)alloc((size_t)B_ * H_ * NCH_ * 64 * 4);
  float* cin  = (float*)alloc((size_t)B_ * H_ * NCH_ * 64 * 4);
  float* part = (float*)alloc((size_t)2 * NBLK_C * 4);   // per-block GN partials
  float* sums = (float*)alloc(64 * 4);
  u16*  on   = xb;   // alias: xb dead after GEMM1, on written in applyD

  // Fail-loud guard: if workspace is too small, do nothing (clean absmax
  // failure with valid timing) instead of corrupting memory / crashing.
  if ((size_t)(p - (char*)d_ws) > ws_size) return;

  const int nq = (BT_ * D_ + NP_ * D_ + D_ * D_) / 4;   // fused cvt quads
  hipLaunchKernelGGL(cvt_all, dim3((nq + 255) / 256), dim3(256), 0, stream,
                     x, W_in, W_out, xb, wb, wob);
  hipLaunchKernelGGL((gemm_bt<true>),  dim3(NP_ / 128, BT_ / 128), dim3(256), 0, stream,
                     xb, wb, (void*)proj, BT_, NP_, D_);
  hipLaunchKernelGGL(scanA_kernel,  dim3(B_ * H_ * NCH_), dim3(64),  0, stream,
                     proj, conv_w, conv_b, decay, vv, ye, Pc, pfx);
  hipLaunchKernelGGL(comb_kernel,   dim3(8),              dim3(256), 0, stream, ye, Pc, cin);
  hipLaunchKernelGGL(applyC_kernel, dim3(NBLK_C),         dim3(256), 0, stream, vv, proj, pfx, cin, part);
  hipLaunchKernelGGL(reduce_kernel, dim3(32),             dim3(256), 0, stream, part, sums);
  hipLaunchKernelGGL(applyD_kernel, dim3(BT_ * D_ / 256), dim3(256), 0, stream, vv, sums, gn_w, gn_b, on);
  hipLaunchKernelGGL((gemm_bt<false>), dim3(D_ / 128, BT_ / 128), dim3(256), 0, stream,
                     on, wob, d_out, BT_, D_, D_);
}

// Round 9
// 183.692 us; speedup vs baseline: 1.1710x; 1.1710x over previous
//
#include <hip/hip_runtime.h>

// ---- problem constants ----
#define D_   1024
#define H_   16
#define T_   2048
#define B_   2
#define BT_  (B_*T_)       // 4096
#define NIN_ 3088          // 3D + H
#define NP_  3200          // padded to 25*128
#define CHUNK_ 64
#define NCH_  (T_/CHUNK_)  // 32 chunks
#define GN_INV (1.0f/131072.0f)  // 1/(K*T)
#define NBLK_C (BT_ * D_ / 256)  // 16384 applyC blocks

typedef unsigned short u16;
typedef __attribute__((ext_vector_type(8))) __bf16 bf16x8;
typedef __attribute__((ext_vector_type(8))) unsigned short u16x8;
typedef __attribute__((ext_vector_type(4))) float  f32x4;

struct __align__(16) F4 { float x, y, z, w; };
struct __align__(8)  U4 { u16 x, y, z, w; };

__device__ inline u16 f2bf(float f) {
  union { float f; unsigned u; } q; q.f = f;
  unsigned r = q.u + 0x7FFFu + ((q.u >> 16) & 1u);   // RNE
  return (u16)(r >> 16);
}
__device__ inline float bf2f(u16 v) {
  union { unsigned u; float f; } q; q.u = ((unsigned)v) << 16; return q.f;
}

__device__ inline void gl_lds16(const void* g, void* l) {
  __builtin_amdgcn_global_load_lds(
      (const __attribute__((address_space(1))) unsigned*)g,
      (__attribute__((address_space(3))) unsigned*)l, 16, 0, 0);
}

// ---------------- fused f32 -> bf16 converts (x, W_in padded, W_out) ----------------
__global__ void cvt_all(const float* __restrict__ x, const float* __restrict__ W_in,
                        const float* __restrict__ W_out,
                        u16* __restrict__ xb, u16* __restrict__ wb, u16* __restrict__ wob) {
  const int nx = BT_ * D_ / 4, nw = NP_ * D_ / 4, no = D_ * D_ / 4;
  int q = blockIdx.x * 256 + threadIdx.x;
  if (q < nx) {
    int i = q * 4;
    F4 f = *reinterpret_cast<const F4*>(x + i);
    U4 u; u.x = f2bf(f.x); u.y = f2bf(f.y); u.z = f2bf(f.z); u.w = f2bf(f.w);
    *reinterpret_cast<U4*>(xb + i) = u;
  } else if (q < nx + nw) {
    int i = (q - nx) * 4;
    int row = i >> 10;
    U4 u; u.x = 0; u.y = 0; u.z = 0; u.w = 0;
    if (row < NIN_) {
      F4 f = *reinterpret_cast<const F4*>(W_in + i);
      u.x = f2bf(f.x); u.y = f2bf(f.y); u.z = f2bf(f.z); u.w = f2bf(f.w);
    }
    *reinterpret_cast<U4*>(wb + i) = u;
  } else if (q < nx + nw + no) {
    int i = (q - nx - nw) * 4;
    F4 f = *reinterpret_cast<const F4*>(W_out + i);
    U4 u; u.x = f2bf(f.x); u.y = f2bf(f.y); u.z = f2bf(f.z); u.w = f2bf(f.w);
    *reinterpret_cast<U4*>(wob + i) = u;
  }
}

// ---------------- bf16 GEMM: C[M,N] = A[M,K] * B[N,K]^T ----------------
// 128x128 tile, BK=64, 4 waves (2x2 of 64x64), mfma_f32_16x16x32_bf16.
// LDS XOR-swizzle (rule 21): linear LDS dest for global_load_lds, source
// 16B-block pre-permuted by blk^(row&7); ds_read applies the same XOR.
// BF16OUT: write C as bf16 (GEMM1->proj), else f32 (GEMM2->d_out).
template<bool BF16OUT>
__global__ __launch_bounds__(256, 2) void gemm_bt(
    const u16* __restrict__ A, const u16* __restrict__ Bm,
    void* __restrict__ Cv, int M, int N, int K) {
  __shared__ __align__(16) u16 As[128 * 64];
  __shared__ __align__(16) u16 Bs[128 * 64];
  const int tid  = threadIdx.x;
  const int lane = tid & 63;
  const int wid  = tid >> 6;
  const int tm = blockIdx.y * 128, tn = blockIdx.x * 128;
  const int wm = (wid >> 1) * 64,  wn = (wid & 1) * 64;
  const int krow = lane & 15;
  const int ksub = (lane >> 4) * 8;
  f32x4 acc[4][4] = {};

  for (int kt = 0; kt < K; kt += 64) {
#pragma unroll
    for (int i = 0; i < 4; ++i) {
      int e = i * 2048 + tid * 8;          // element idx in [128][64] tile
      int r = e >> 6;
      int c = (((tid & 7) ^ (r & 7)) << 3); // pre-swizzled source column
      gl_lds16(A  + (size_t)(tm + r) * K + kt + c, &As[e]);
      gl_lds16(Bm + (size_t)(tn + r) * K + kt + c, &Bs[e]);
    }
    __syncthreads();                        // drains vmcnt before ds_read
#pragma unroll
    for (int kk = 0; kk < 64; kk += 32) {
      bf16x8 af[4], bfr[4];
#pragma unroll
      for (int i = 0; i < 4; ++i) {
        int row = wm + i * 16 + krow;
        int b = (((kk + ksub) >> 3) ^ (row & 7)) << 3;
        af[i] = *reinterpret_cast<const bf16x8*>(&As[row * 64 + b]);
      }
#pragma unroll
      for (int i = 0; i < 4; ++i) {
        int row = wn + i * 16 + krow;
        int b = (((kk + ksub) >> 3) ^ (row & 7)) << 3;
        bfr[i] = *reinterpret_cast<const bf16x8*>(&Bs[row * 64 + b]);
      }
#pragma unroll
      for (int mi = 0; mi < 4; ++mi)
#pragma unroll
        for (int ni = 0; ni < 4; ++ni)
          acc[mi][ni] = __builtin_amdgcn_mfma_f32_16x16x32_bf16(af[mi], bfr[ni], acc[mi][ni], 0, 0, 0);
    }
    __syncthreads();
  }
  // C/D layout (m89-verified): col = lane&15, row = (lane>>4)*4 + j
  const int rb = tm + wm + (lane >> 4) * 4;
  const int cb = tn + wn + (lane & 15);
#pragma unroll
  for (int mi = 0; mi < 4; ++mi)
#pragma unroll
    for (int ni = 0; ni < 4; ++ni)
#pragma unroll
      for (int j = 0; j < 4; ++j) {
        size_t off = (size_t)(rb + mi * 16 + j) * N + cb + ni * 16;
        if constexpr (BF16OUT) ((u16*)Cv)[off] = f2bf(acc[mi][ni][j]);
        else                   ((float*)Cv)[off] = acc[mi][ni][j];
      }
}

// ---------------- fused conv+silu+decay + chunk-local scan (LDS-staged) ----------------
// grid: (b,h,c) = 2*16*32 blocks of 64 threads (one k-channel per lane).
// Phase 1: bulk-stage chunk's v[64 rows] and k[72 rows] columns into LDS with
//          wide 16B loads (all independent -> single latency exposure).
// Phase 2: serial scan reads LDS (ds_read_u16, rolling 4-reg conv window).
__global__ void scanA_kernel(const u16* __restrict__ proj,
                             const float* __restrict__ conv_w,
                             const float* __restrict__ conv_b,
                             const float* __restrict__ decay,
                             float* __restrict__ vv,
                             float* __restrict__ ye, float* __restrict__ Pc,
                             float* __restrict__ pfx) {
  __shared__ __align__(16) u16 lv[CHUNK_ * 64];        // v rows t0..t0+63
  __shared__ __align__(16) u16 lk[(CHUNK_ + 8) * 64];  // k rows t0-6..t0+65
  int bh = blockIdx.x >> 5, c = blockIdx.x & 31;
  int b = bh >> 4, h = bh & 15;
  int k = threadIdx.x;                 // 64 lanes
  int d0 = h * 64;
  int t0 = c * CHUNK_;
  int rsub = k >> 3, cblk = (k & 7) * 8;
  // ---- stage v: 8 x 16B per lane ----
#pragma unroll
  for (int it = 0; it < 8; ++it) {
    int r = it * 8 + rsub;
    *reinterpret_cast<u16x8*>(&lv[r * 64 + cblk]) =
      *reinterpret_cast<const u16x8*>(&proj[(size_t)(b * T_ + t0 + r) * NP_ + 1024 + d0 + cblk]);
  }
  // ---- stage k rows t0-6 .. t0+65 (72 rows, used 0..66), zero-guarded ----
#pragma unroll
  for (int it = 0; it < 9; ++it) {
    int r = it * 8 + rsub;
    int tt = t0 + r - 6;
    u16x8 kv = {0, 0, 0, 0, 0, 0, 0, 0};
    if (tt >= 0 && tt < T_)
      kv = *reinterpret_cast<const u16x8*>(&proj[(size_t)(b * T_ + tt) * NP_ + 2048 + d0 + cblk]);
    *reinterpret_cast<u16x8*>(&lk[r * 64 + cblk]) = kv;
  }
  // ---- per-lane decay factor: lane L holds a for t = t0+L ----
  float wv = bf2f(proj[(size_t)(b * T_ + t0 + k) * NP_ + 3072 + h]);
  float gte = 1.f / (1.f + __expf(-(decay[h] + wv)));
  float my_a = __expf(-8.f * (1.f - gte) - 0.1f);
  int d = d0 + k;
  float cw0 = conv_w[d * 4], cw1 = conv_w[d * 4 + 1],
        cw2 = conv_w[d * 4 + 2], cw3 = conv_w[d * 4 + 3];
  float cb = conv_b[d];
  __syncthreads();
  // ---- serial scan from LDS ----
  float* V = vv + ((size_t)bh * T_ + t0) * 64 + k;
  float k0 = bf2f(lk[0 * 64 + k]), k1 = bf2f(lk[1 * 64 + k]), k2 = bf2f(lk[2 * 64 + k]);
  float y = 0.f, pf = 1.f, my_pf = 1.f;
#pragma unroll
  for (int i = 0; i < CHUNK_; ++i) {
    float k3 = bf2f(lk[(i + 3) * 64 + k]);
    float v  = bf2f(lv[i * 64 + k]);
    float kc = cb;
    kc = fmaf(k0, cw0, kc); kc = fmaf(k1, cw1, kc);
    kc = fmaf(k2, cw2, kc); kc = fmaf(k3, cw3, kc);
    float sil = kc / (1.f + __expf(-kc));
    float g = v * sil * (1.f / 32.f);
    float a = __shfl(my_a, i);
    y = fmaf(a, y, g);                 // y = g + a*y_prev
    V[(size_t)i * 64] = y;
    pf *= a;
    if (i == k) my_pf = pf;
    k0 = k1; k1 = k2; k2 = k3;
  }
  pfx[(size_t)bh * T_ + t0 + k] = my_pf;
  ye[(size_t)blockIdx.x * 64 + k] = y;
  Pc[(size_t)blockIdx.x * 64 + k] = pf;
}

// ---------------- cross-chunk combine (tiny) ----------------
__global__ void comb_kernel(const float* __restrict__ ye, const float* __restrict__ Pc,
                            float* __restrict__ cin) {
  int g = blockIdx.x * 256 + threadIdx.x;      // 2048 = (b,h,k)
  int bh = g >> 6, k = g & 63;
  float s = 0.f;
  for (int c = 0; c < NCH_; ++c) {
    size_t i = ((size_t)bh * NCH_ + c) * 64 + k;
    cin[i] = s;
    s = ye[i] + Pc[i] * s;
  }
}

// ---------------- phase C: add carry, out = silu(r)*y, GN partials (no atomics) ----------------
__global__ void applyC_kernel(float* __restrict__ y, const u16* __restrict__ proj,
                              const float* __restrict__ pfx, const float* __restrict__ cin,
                              float* __restrict__ part) {
  int idx = blockIdx.x * 256 + threadIdx.x;    // (bh,t,k) linear
  int k  = idx & 63;
  int t  = (idx >> 6) & 2047;
  int bh = idx >> 17;                          // 256 threads share one bh
  int b = bh >> 4, h = bh & 15;
  float ci = cin[(((size_t)bh * NCH_) + (t >> 6)) * 64 + k];
  float yf = fmaf(pfx[(size_t)bh * T_ + t], ci, y[idx]);
  float r = bf2f(proj[(size_t)(b * T_ + t) * NP_ + h * 64 + k]);
  float o = yf * (r / (1.f + __expf(-r)));
  y[idx] = o;
  // block reduce sum / sumsq -> contention-free per-block partials
  float s1 = o, s2 = o * o;
#pragma unroll
  for (int m = 32; m; m >>= 1) { s1 += __shfl_xor(s1, m); s2 += __shfl_xor(s2, m); }
  __shared__ float ps[8];
  int wid = threadIdx.x >> 6, lane = threadIdx.x & 63;
  if (lane == 0) { ps[wid] = s1; ps[4 + wid] = s2; }
  __syncthreads();
  if (threadIdx.x == 0) {
    part[blockIdx.x]          = ps[0] + ps[1] + ps[2] + ps[3];
    part[NBLK_C + blockIdx.x] = ps[4] + ps[5] + ps[6] + ps[7];
  }
}

// ---------------- reduce partials -> sums[bh], sums[32+bh] ----------------
// applyC block b has bh = b>>9 (512 blocks per bh, contiguous)
__global__ void reduce_kernel(const float* __restrict__ part, float* __restrict__ sums) {
  int bh = blockIdx.x;                         // 32 blocks, 256 threads
  int t = threadIdx.x;
  int base = bh * 512;
  float s1 = part[base + t]           + part[base + 256 + t];
  float s2 = part[NBLK_C + base + t]  + part[NBLK_C + base + 256 + t];
#pragma unroll
  for (int m = 32; m; m >>= 1) { s1 += __shfl_xor(s1, m); s2 += __shfl_xor(s2, m); }
  __shared__ float ps[8];
  int wid = t >> 6, lane = t & 63;
  if (lane == 0) { ps[wid] = s1; ps[4 + wid] = s2; }
  __syncthreads();
  if (t == 0) {
    sums[bh]      = ps[0] + ps[1] + ps[2] + ps[3];
    sums[32 + bh] = ps[4] + ps[5] + ps[6] + ps[7];
  }
}

// ---------------- phase D: normalize + bf16 cast to (b,t,d) ----------------
__global__ void applyD_kernel(const float* __restrict__ o, const float* __restrict__ sums,
                              const float* __restrict__ gn_w, const float* __restrict__ gn_b,
                              u16* __restrict__ on) {
  int idx = blockIdx.x * 256 + threadIdx.x;    // (bh,t,k) linear
  int k  = idx & 63;
  int t  = (idx >> 6) & 2047;
  int bh = idx >> 17;
  int b = bh >> 4, h = bh & 15;
  float mean = sums[bh] * GN_INV;
  float var  = sums[32 + bh] * GN_INV - mean * mean;
  float inv  = rsqrtf(var + 1e-5f);
  int d = h * 64 + k;
  float val = (o[idx] - mean) * inv * gn_w[d] + gn_b[d];
  on[(size_t)(b * T_ + t) * D_ + d] = f2bf(val);
}

// ---------------- launch ----------------
extern "C" void kernel_launch(void* const* d_in, const int* in_sizes, int n_in,
                              void* d_out, int out_size, void* d_ws, size_t ws_size,
                              hipStream_t stream) {
  const float* x      = (const float*)d_in[0];
  const float* W_in   = (const float*)d_in[1];
  const float* conv_w = (const float*)d_in[2];
  const float* conv_b = (const float*)d_in[3];
  const float* decay  = (const float*)d_in[4];
  const float* gn_w   = (const float*)d_in[5];
  const float* gn_b   = (const float*)d_in[6];
  const float* W_out  = (const float*)d_in[7];

  char* p = (char*)d_ws;
  auto alloc = [&](size_t bytes) { void* r = (void*)p; p += (bytes + 255) & ~(size_t)255; return r; };
  u16*  xb   = (u16*)alloc((size_t)BT_ * D_ * 2);   // also reused as `on` after GEMM1
  u16*  wb   = (u16*)alloc((size_t)NP_ * D_ * 2);
  u16*  wob  = (u16*)alloc((size_t)D_ * D_ * 2);
  u16*  proj = (u16*)alloc((size_t)BT_ * NP_ * 2);  // bf16 proj
  float* vv   = (float*)alloc((size_t)BT_ * D_ * 4);
  float* pfx  = (float*)alloc((size_t)B_ * H_ * T_ * 4);
  float* ye   = (float*)alloc((size_t)B_ * H_ * NCH_ * 64 * 4);
  float* Pc   = (float*)alloc((size_t)B_ * H_ * NCH_ * 64 * 4);
  float* cin  = (float*)alloc((size_t)B_ * H_ * NCH_ * 64 * 4);
  float* part = (float*)alloc((size_t)2 * NBLK_C * 4);   // per-block GN partials
  float* sums = (float*)alloc(64 * 4);
  u16*  on   = xb;   // alias: xb dead after GEMM1, on written in applyD

  // Fail-loud guard: if workspace is too small, do nothing (clean absmax
  // failure with valid timing) instead of corrupting memory / crashing.
  if ((size_t)(p - (char*)d_ws) > ws_size) return;

  const int nq = (BT_ * D_ + NP_ * D_ + D_ * D_) / 4;   // fused cvt quads
  hipLaunchKernelGGL(cvt_all, dim3((nq + 255) / 256), dim3(256), 0, stream,
                     x, W_in, W_out, xb, wb, wob);
  hipLaunchKernelGGL((gemm_bt<true>),  dim3(NP_ / 128, BT_ / 128), dim3(256), 0, stream,
                     xb, wb, (void*)proj, BT_, NP_, D_);
  hipLaunchKernelGGL(scanA_kernel,  dim3(B_ * H_ * NCH_), dim3(64),  0, stream,
                     proj, conv_w, conv_b, decay, vv, ye, Pc, pfx);
  hipLaunchKernelGGL(comb_kernel,   dim3(8),              dim3(256), 0, stream, ye, Pc, cin);
  hipLaunchKernelGGL(applyC_kernel, dim3(NBLK_C),         dim3(256), 0, stream, vv, proj, pfx, cin, part);
  hipLaunchKernelGGL(reduce_kernel, dim3(32),             dim3(256), 0, stream, part, sums);
  hipLaunchKernelGGL(applyD_kernel, dim3(BT_ * D_ / 256), dim3(256), 0, stream, vv, sums, gn_w, gn_b, on);
  hipLaunchKernelGGL((gemm_bt<false>), dim3(D_ / 128, BT_ / 128), dim3(256), 0, stream,
                     on, wob, d_out, BT_, D_, D_);
}

// Round 10
// 176.042 us; speedup vs baseline: 1.2218x; 1.0435x over previous
//
#include <hip/hip_runtime.h>

// ---- problem constants ----
#define D_   1024
#define H_   16
#define T_   2048
#define B_   2
#define BT_  (B_*T_)       // 4096
#define NIN_ 3088          // 3D + H
#define NP_  3200          // padded to 25*128
#define CHUNK_ 64
#define NCH_  (T_/CHUNK_)  // 32 chunks
#define GN_INV (1.0f/131072.0f)  // 1/(K*T)
#define NBLK_C 4096              // applyC blocks (4 elems/thread)

typedef unsigned short u16;
typedef __attribute__((ext_vector_type(8))) __bf16 bf16x8;
typedef __attribute__((ext_vector_type(8))) unsigned short u16x8;
typedef __attribute__((ext_vector_type(4))) unsigned short u16x4;
typedef __attribute__((ext_vector_type(4))) float  f32x4;

struct __align__(16) F4 { float x, y, z, w; };
struct __align__(8)  U4 { u16 x, y, z, w; };

__device__ inline u16 f2bf(float f) {
  union { float f; unsigned u; } q; q.f = f;
  unsigned r = q.u + 0x7FFFu + ((q.u >> 16) & 1u);   // RNE
  return (u16)(r >> 16);
}
__device__ inline float bf2f(u16 v) {
  union { unsigned u; float f; } q; q.u = ((unsigned)v) << 16; return q.f;
}

__device__ inline void gl_lds16(const void* g, void* l) {
  __builtin_amdgcn_global_load_lds(
      (const __attribute__((address_space(1))) unsigned*)g,
      (__attribute__((address_space(3))) unsigned*)l, 16, 0, 0);
}

// ---------------- fused f32 -> bf16 converts (x, W_in padded, W_out) ----------------
__global__ void cvt_all(const float* __restrict__ x, const float* __restrict__ W_in,
                        const float* __restrict__ W_out,
                        u16* __restrict__ xb, u16* __restrict__ wb, u16* __restrict__ wob) {
  const int nx = BT_ * D_ / 4, nw = NP_ * D_ / 4, no = D_ * D_ / 4;
  int q = blockIdx.x * 256 + threadIdx.x;
  if (q < nx) {
    int i = q * 4;
    F4 f = *reinterpret_cast<const F4*>(x + i);
    U4 u; u.x = f2bf(f.x); u.y = f2bf(f.y); u.z = f2bf(f.z); u.w = f2bf(f.w);
    *reinterpret_cast<U4*>(xb + i) = u;
  } else if (q < nx + nw) {
    int i = (q - nx) * 4;
    int row = i >> 10;
    U4 u; u.x = 0; u.y = 0; u.z = 0; u.w = 0;
    if (row < NIN_) {
      F4 f = *reinterpret_cast<const F4*>(W_in + i);
      u.x = f2bf(f.x); u.y = f2bf(f.y); u.z = f2bf(f.z); u.w = f2bf(f.w);
    }
    *reinterpret_cast<U4*>(wb + i) = u;
  } else if (q < nx + nw + no) {
    int i = (q - nx - nw) * 4;
    F4 f = *reinterpret_cast<const F4*>(W_out + i);
    U4 u; u.x = f2bf(f.x); u.y = f2bf(f.y); u.z = f2bf(f.z); u.w = f2bf(f.w);
    *reinterpret_cast<U4*>(wob + i) = u;
  }
}

// ---------------- bf16 GEMM: C[M,N] = A[M,K] * B[N,K]^T ----------------
// 128x128 tile, BK=64, 4 waves (2x2 of 64x64), mfma_f32_16x16x32_bf16.
// LDS XOR-swizzle (rule 21): linear LDS dest for global_load_lds, source
// 16B-block pre-permuted by blk^(row&7); ds_read applies the same XOR.
// BF16OUT: write C as bf16 (GEMM1->proj), else f32 (GEMM2->d_out).
template<bool BF16OUT>
__global__ __launch_bounds__(256, 2) void gemm_bt(
    const u16* __restrict__ A, const u16* __restrict__ Bm,
    void* __restrict__ Cv, int M, int N, int K) {
  __shared__ __align__(16) u16 As[128 * 64];
  __shared__ __align__(16) u16 Bs[128 * 64];
  const int tid  = threadIdx.x;
  const int lane = tid & 63;
  const int wid  = tid >> 6;
  const int tm = blockIdx.y * 128, tn = blockIdx.x * 128;
  const int wm = (wid >> 1) * 64,  wn = (wid & 1) * 64;
  const int krow = lane & 15;
  const int ksub = (lane >> 4) * 8;
  f32x4 acc[4][4] = {};

  for (int kt = 0; kt < K; kt += 64) {
#pragma unroll
    for (int i = 0; i < 4; ++i) {
      int e = i * 2048 + tid * 8;          // element idx in [128][64] tile
      int r = e >> 6;
      int c = (((tid & 7) ^ (r & 7)) << 3); // pre-swizzled source column
      gl_lds16(A  + (size_t)(tm + r) * K + kt + c, &As[e]);
      gl_lds16(Bm + (size_t)(tn + r) * K + kt + c, &Bs[e]);
    }
    __syncthreads();                        // drains vmcnt before ds_read
#pragma unroll
    for (int kk = 0; kk < 64; kk += 32) {
      bf16x8 af[4], bfr[4];
#pragma unroll
      for (int i = 0; i < 4; ++i) {
        int row = wm + i * 16 + krow;
        int b = (((kk + ksub) >> 3) ^ (row & 7)) << 3;
        af[i] = *reinterpret_cast<const bf16x8*>(&As[row * 64 + b]);
      }
#pragma unroll
      for (int i = 0; i < 4; ++i) {
        int row = wn + i * 16 + krow;
        int b = (((kk + ksub) >> 3) ^ (row & 7)) << 3;
        bfr[i] = *reinterpret_cast<const bf16x8*>(&Bs[row * 64 + b]);
      }
#pragma unroll
      for (int mi = 0; mi < 4; ++mi)
#pragma unroll
        for (int ni = 0; ni < 4; ++ni)
          acc[mi][ni] = __builtin_amdgcn_mfma_f32_16x16x32_bf16(af[mi], bfr[ni], acc[mi][ni], 0, 0, 0);
    }
    __syncthreads();
  }
  // C/D layout (m89-verified): col = lane&15, row = (lane>>4)*4 + j
  const int rb = tm + wm + (lane >> 4) * 4;
  const int cb = tn + wn + (lane & 15);
#pragma unroll
  for (int mi = 0; mi < 4; ++mi)
#pragma unroll
    for (int ni = 0; ni < 4; ++ni)
#pragma unroll
      for (int j = 0; j < 4; ++j) {
        size_t off = (size_t)(rb + mi * 16 + j) * N + cb + ni * 16;
        if constexpr (BF16OUT) ((u16*)Cv)[off] = f2bf(acc[mi][ni][j]);
        else                   ((float*)Cv)[off] = acc[mi][ni][j];
      }
}

// ---------------- fused conv+silu+decay + chunk-local scan (LDS-staged) ----------------
// grid: (b,h,c) = 2*16*32 blocks of 64 threads (one k-channel per lane).
// Phase 1: bulk-stage chunk's v[64 rows] and k[72 rows] columns into LDS with
//          wide 16B loads (all independent -> single latency exposure).
// Phase 2: serial scan reads LDS; y written to vv as bf16.
__global__ void scanA_kernel(const u16* __restrict__ proj,
                             const float* __restrict__ conv_w,
                             const float* __restrict__ conv_b,
                             const float* __restrict__ decay,
                             u16* __restrict__ vv,
                             float* __restrict__ ye, float* __restrict__ Pc,
                             float* __restrict__ pfx) {
  __shared__ __align__(16) u16 lv[CHUNK_ * 64];        // v rows t0..t0+63
  __shared__ __align__(16) u16 lk[(CHUNK_ + 8) * 64];  // k rows t0-6..t0+65
  int bh = blockIdx.x >> 5, c = blockIdx.x & 31;
  int b = bh >> 4, h = bh & 15;
  int k = threadIdx.x;                 // 64 lanes
  int d0 = h * 64;
  int t0 = c * CHUNK_;
  int rsub = k >> 3, cblk = (k & 7) * 8;
  // ---- stage v: 8 x 16B per lane ----
#pragma unroll
  for (int it = 0; it < 8; ++it) {
    int r = it * 8 + rsub;
    *reinterpret_cast<u16x8*>(&lv[r * 64 + cblk]) =
      *reinterpret_cast<const u16x8*>(&proj[(size_t)(b * T_ + t0 + r) * NP_ + 1024 + d0 + cblk]);
  }
  // ---- stage k rows t0-6 .. t0+65 (72 rows, used 0..66), zero-guarded ----
#pragma unroll
  for (int it = 0; it < 9; ++it) {
    int r = it * 8 + rsub;
    int tt = t0 + r - 6;
    u16x8 kv = {0, 0, 0, 0, 0, 0, 0, 0};
    if (tt >= 0 && tt < T_)
      kv = *reinterpret_cast<const u16x8*>(&proj[(size_t)(b * T_ + tt) * NP_ + 2048 + d0 + cblk]);
    *reinterpret_cast<u16x8*>(&lk[r * 64 + cblk]) = kv;
  }
  // ---- per-lane decay factor: lane L holds a for t = t0+L ----
  float wv = bf2f(proj[(size_t)(b * T_ + t0 + k) * NP_ + 3072 + h]);
  float gte = 1.f / (1.f + __expf(-(decay[h] + wv)));
  float my_a = __expf(-8.f * (1.f - gte) - 0.1f);
  int d = d0 + k;
  float cw0 = conv_w[d * 4], cw1 = conv_w[d * 4 + 1],
        cw2 = conv_w[d * 4 + 2], cw3 = conv_w[d * 4 + 3];
  float cb = conv_b[d];
  __syncthreads();
  // ---- serial scan from LDS ----
  u16* V = vv + ((size_t)bh * T_ + t0) * 64 + k;
  float k0 = bf2f(lk[0 * 64 + k]), k1 = bf2f(lk[1 * 64 + k]), k2 = bf2f(lk[2 * 64 + k]);
  float y = 0.f, pf = 1.f, my_pf = 1.f;
#pragma unroll
  for (int i = 0; i < CHUNK_; ++i) {
    float k3 = bf2f(lk[(i + 3) * 64 + k]);
    float v  = bf2f(lv[i * 64 + k]);
    float kc = cb;
    kc = fmaf(k0, cw0, kc); kc = fmaf(k1, cw1, kc);
    kc = fmaf(k2, cw2, kc); kc = fmaf(k3, cw3, kc);
    float sil = kc / (1.f + __expf(-kc));
    float g = v * sil * (1.f / 32.f);
    float a = __shfl(my_a, i);
    y = fmaf(a, y, g);                 // y = g + a*y_prev (state stays f32)
    V[(size_t)i * 64] = f2bf(y);       // output rounds to bf16
    pf *= a;
    if (i == k) my_pf = pf;
    k0 = k1; k1 = k2; k2 = k3;
  }
  pfx[(size_t)bh * T_ + t0 + k] = my_pf;
  ye[(size_t)blockIdx.x * 64 + k] = y;
  Pc[(size_t)blockIdx.x * 64 + k] = pf;
}

// ---------------- cross-chunk combine (tiny, x4 vectorized) ----------------
__global__ void comb_kernel(const float* __restrict__ ye, const float* __restrict__ Pc,
                            float* __restrict__ cin) {
  int g4 = blockIdx.x * 256 + threadIdx.x;     // 512 = (b,h,k/4)
  int bh = g4 >> 4, k4 = (g4 & 15) * 4;
  f32x4 s = {0.f, 0.f, 0.f, 0.f};
  for (int c = 0; c < NCH_; ++c) {
    size_t i = ((size_t)bh * NCH_ + c) * 64 + k4;
    *reinterpret_cast<f32x4*>(&cin[i]) = s;
    f32x4 e = *reinterpret_cast<const f32x4*>(&ye[i]);
    f32x4 p = *reinterpret_cast<const f32x4*>(&Pc[i]);
    s = e + p * s;
  }
}

// ---------------- phase C: add carry, out = silu(r)*y, GN partials (x4) ----------------
__global__ void applyC_kernel(const u16* __restrict__ vv, const u16* __restrict__ proj,
                              const float* __restrict__ pfx, const float* __restrict__ cin,
                              u16* __restrict__ ob, float* __restrict__ part) {
  int idx4 = blockIdx.x * 256 + threadIdx.x;   // (bh,t,k/4) linear
  int k4 = (idx4 & 15) * 4;
  int t  = (idx4 >> 4) & 2047;
  int bh = idx4 >> 15;
  int b = bh >> 4, h = bh & 15;
  size_t ebase = ((size_t)bh * T_ + t) * 64 + k4;
  f32x4 ci = *reinterpret_cast<const f32x4*>(&cin[(((size_t)bh * NCH_) + (t >> 6)) * 64 + k4]);
  float px = pfx[(size_t)bh * T_ + t];
  u16x4 yv = *reinterpret_cast<const u16x4*>(&vv[ebase]);
  u16x4 rv = *reinterpret_cast<const u16x4*>(&proj[(size_t)(b * T_ + t) * NP_ + h * 64 + k4]);
  u16x4 ov;
  float s1 = 0.f, s2 = 0.f;
#pragma unroll
  for (int j = 0; j < 4; ++j) {
    float yf = fmaf(px, ci[j], bf2f(yv[j]));
    float r = bf2f(rv[j]);
    float o = yf * (r / (1.f + __expf(-r)));
    ov[j] = f2bf(o);
    s1 += o; s2 += o * o;
  }
  *reinterpret_cast<u16x4*>(&ob[ebase]) = ov;
  // block reduce sum / sumsq -> contention-free per-block partials
#pragma unroll
  for (int m = 32; m; m >>= 1) { s1 += __shfl_xor(s1, m); s2 += __shfl_xor(s2, m); }
  __shared__ float ps[8];
  int wid = threadIdx.x >> 6, lane = threadIdx.x & 63;
  if (lane == 0) { ps[wid] = s1; ps[4 + wid] = s2; }
  __syncthreads();
  if (threadIdx.x == 0) {
    part[blockIdx.x]          = ps[0] + ps[1] + ps[2] + ps[3];
    part[NBLK_C + blockIdx.x] = ps[4] + ps[5] + ps[6] + ps[7];
  }
}

// ---------------- reduce partials -> sums[bh], sums[32+bh] ----------------
// applyC block b covers bh = b>>7 (128 blocks per bh, contiguous); 1-wave blocks
__global__ void reduce_kernel(const float* __restrict__ part, float* __restrict__ sums) {
  int bh = blockIdx.x;                         // 32 blocks, 64 threads
  int t = threadIdx.x;
  int base = bh * 128;
  float s1 = part[base + t]           + part[base + 64 + t];
  float s2 = part[NBLK_C + base + t]  + part[NBLK_C + base + 64 + t];
#pragma unroll
  for (int m = 32; m; m >>= 1) { s1 += __shfl_xor(s1, m); s2 += __shfl_xor(s2, m); }
  if (t == 0) { sums[bh] = s1; sums[32 + bh] = s2; }
}

// ---------------- phase D: normalize + bf16 cast to (b,t,d) (x4) ----------------
__global__ void applyD_kernel(const u16* __restrict__ ob, const float* __restrict__ sums,
                              const float* __restrict__ gn_w, const float* __restrict__ gn_b,
                              u16* __restrict__ on) {
  int idx4 = blockIdx.x * 256 + threadIdx.x;   // (bh,t,k/4) linear
  int k4 = (idx4 & 15) * 4;
  int t  = (idx4 >> 4) & 2047;
  int bh = idx4 >> 15;
  int b = bh >> 4, h = bh & 15;
  float mean = sums[bh] * GN_INV;
  float var  = sums[32 + bh] * GN_INV - mean * mean;
  float inv  = rsqrtf(var + 1e-5f);
  int d = h * 64 + k4;
  u16x4 o = *reinterpret_cast<const u16x4*>(&ob[((size_t)bh * T_ + t) * 64 + k4]);
  F4 gw = *reinterpret_cast<const F4*>(&gn_w[d]);
  F4 gb = *reinterpret_cast<const F4*>(&gn_b[d]);
  u16x4 r;
  r[0] = f2bf((bf2f(o[0]) - mean) * inv * gw.x + gb.x);
  r[1] = f2bf((bf2f(o[1]) - mean) * inv * gw.y + gb.y);
  r[2] = f2bf((bf2f(o[2]) - mean) * inv * gw.z + gb.z);
  r[3] = f2bf((bf2f(o[3]) - mean) * inv * gw.w + gb.w);
  *reinterpret_cast<u16x4*>(&on[(size_t)(b * T_ + t) * D_ + d]) = r;
}

// ---------------- launch ----------------
extern "C" void kernel_launch(void* const* d_in, const int* in_sizes, int n_in,
                              void* d_out, int out_size, void* d_ws, size_t ws_size,
                              hipStream_t stream) {
  const float* x      = (const float*)d_in[0];
  const float* W_in   = (const float*)d_in[1];
  const float* conv_w = (const float*)d_in[2];
  const float* conv_b = (const float*)d_in[3];
  const float* decay  = (const float*)d_in[4];
  const float* gn_w   = (const float*)d_in[5];
  const float* gn_b   = (const float*)d_in[6];
  const float* W_out  = (const float*)d_in[7];

  char* p = (char*)d_ws;
  auto alloc = [&](size_t bytes) { void* r = (void*)p; p += (bytes + 255) & ~(size_t)255; return r; };
  u16*  xb   = (u16*)alloc((size_t)BT_ * D_ * 2);   // also reused as `on` after GEMM1
  u16*  wb   = (u16*)alloc((size_t)NP_ * D_ * 2);
  u16*  wob  = (u16*)alloc((size_t)D_ * D_ * 2);
  u16*  proj = (u16*)alloc((size_t)BT_ * NP_ * 2);  // bf16 proj
  u16*  vv   = (u16*)alloc((size_t)BT_ * D_ * 2);   // bf16 scan output
  u16*  ob   = (u16*)alloc((size_t)BT_ * D_ * 2);   // bf16 gated output
  float* pfx  = (float*)alloc((size_t)B_ * H_ * T_ * 4);
  float* ye   = (float*)alloc((size_t)B_ * H_ * NCH_ * 64 * 4);
  float* Pc   = (float*)alloc((size_t)B_ * H_ * NCH_ * 64 * 4);
  float* cin  = (float*)alloc((size_t)B_ * H_ * NCH_ * 64 * 4);
  float* part = (float*)alloc((size_t)2 * NBLK_C * 4);   // per-block GN partials
  float* sums = (float*)alloc(64 * 4);
  u16*  on   = xb;   // alias: xb dead after GEMM1, on written in applyD

  // Fail-loud guard: if workspace is too small, do nothing (clean absmax
  // failure with valid timing) instead of corrupting memory / crashing.
  if ((size_t)(p - (char*)d_ws) > ws_size) return;

  const int nq = (BT_ * D_ + NP_ * D_ + D_ * D_) / 4;   // fused cvt quads
  hipLaunchKernelGGL(cvt_all, dim3((nq + 255) / 256), dim3(256), 0, stream,
                     x, W_in, W_out, xb, wb, wob);
  hipLaunchKernelGGL((gemm_bt<true>),  dim3(NP_ / 128, BT_ / 128), dim3(256), 0, stream,
                     xb, wb, (void*)proj, BT_, NP_, D_);
  hipLaunchKernelGGL(scanA_kernel,  dim3(B_ * H_ * NCH_), dim3(64),  0, stream,
                     proj, conv_w, conv_b, decay, vv, ye, Pc, pfx);
  hipLaunchKernelGGL(comb_kernel,   dim3(2),              dim3(256), 0, stream, ye, Pc, cin);
  hipLaunchKernelGGL(applyC_kernel, dim3(NBLK_C),         dim3(256), 0, stream, vv, proj, pfx, cin, ob, part);
  hipLaunchKernelGGL(reduce_kernel, dim3(32),             dim3(64),  0, stream, part, sums);
  hipLaunchKernelGGL(applyD_kernel, dim3(BT_ * D_ / 1024), dim3(256), 0, stream, ob, sums, gn_w, gn_b, on);
  hipLaunchKernelGGL((gemm_bt<false>), dim3(D_ / 128, BT_ / 128), dim3(256), 0, stream,
                     on, wob, d_out, BT_, D_, D_);
}

// Round 12
// 171.567 us; speedup vs baseline: 1.2537x; 1.0261x over previous
//
#include <hip/hip_runtime.h>

// ---- problem constants ----
#define D_   1024
#define H_   16
#define T_   2048
#define B_   2
#define BT_  (B_*T_)       // 4096
#define NIN_ 3088          // 3D + H
#define NP_  3200          // padded to 25*128
#define CHUNK_ 64
#define NCH_  (T_/CHUNK_)  // 32 chunks
#define GN_INV (1.0f/131072.0f)  // 1/(K*T)
#define NBLK_C 2048              // applyC blocks (8 elems/thread)

typedef unsigned short u16;
typedef __attribute__((ext_vector_type(8))) __bf16 bf16x8;
typedef __attribute__((ext_vector_type(8))) unsigned short u16x8;
typedef __attribute__((ext_vector_type(4))) unsigned short u16x4;
typedef __attribute__((ext_vector_type(4))) float  f32x4;

struct __align__(16) F4 { float x, y, z, w; };
struct __align__(8)  U4 { u16 x, y, z, w; };

__device__ inline u16 f2bf(float f) {
  union { float f; unsigned u; } q; q.f = f;
  unsigned r = q.u + 0x7FFFu + ((q.u >> 16) & 1u);   // RNE
  return (u16)(r >> 16);
}
__device__ inline float bf2f(u16 v) {
  union { unsigned u; float f; } q; q.u = ((unsigned)v) << 16; return q.f;
}

__device__ inline void gl_lds16(const void* g, void* l) {
  __builtin_amdgcn_global_load_lds(
      (const __attribute__((address_space(1))) unsigned*)g,
      (__attribute__((address_space(3))) unsigned*)l, 16, 0, 0);
}

// ---------------- fused f32 -> bf16 converts (x, W_in padded, W_out) ----------------
__global__ void cvt_all(const float* __restrict__ x, const float* __restrict__ W_in,
                        const float* __restrict__ W_out,
                        u16* __restrict__ xb, u16* __restrict__ wb, u16* __restrict__ wob) {
  const int nx = BT_ * D_ / 4, nw = NP_ * D_ / 4, no = D_ * D_ / 4;
  int q = blockIdx.x * 256 + threadIdx.x;
  if (q < nx) {
    int i = q * 4;
    F4 f = *reinterpret_cast<const F4*>(x + i);
    U4 u; u.x = f2bf(f.x); u.y = f2bf(f.y); u.z = f2bf(f.z); u.w = f2bf(f.w);
    *reinterpret_cast<U4*>(xb + i) = u;
  } else if (q < nx + nw) {
    int i = (q - nx) * 4;
    int row = i >> 10;
    U4 u; u.x = 0; u.y = 0; u.z = 0; u.w = 0;
    if (row < NIN_) {
      F4 f = *reinterpret_cast<const F4*>(W_in + i);
      u.x = f2bf(f.x); u.y = f2bf(f.y); u.z = f2bf(f.z); u.w = f2bf(f.w);
    }
    *reinterpret_cast<U4*>(wb + i) = u;
  } else if (q < nx + nw + no) {
    int i = (q - nx - nw) * 4;
    F4 f = *reinterpret_cast<const F4*>(W_out + i);
    U4 u; u.x = f2bf(f.x); u.y = f2bf(f.y); u.z = f2bf(f.z); u.w = f2bf(f.w);
    *reinterpret_cast<U4*>(wob + i) = u;
  }
}

// ---------------- bf16 GEMM: C[M,N] = A[M,K] * B[N,K]^T ----------------
// 128xTN tile, BK=64, 4 waves (2x2 of 64x(TN/2)), mfma_f32_16x16x32_bf16.
// LDS XOR-swizzle (rule 21): linear LDS dest for global_load_lds, source
// 16B-block pre-permuted by blk^(row&7); ds_read applies the same XOR.
// 1D grid with bijective XCD swizzle (nwg % 8 == 0 for both call sites).
// BF16OUT: write C as bf16 (GEMM1->proj), else f32 (GEMM2->d_out).
template<bool BF16OUT, int TN>
__global__ __launch_bounds__(256, 2) void gemm_bt(
    const u16* __restrict__ A, const u16* __restrict__ Bm,
    void* __restrict__ Cv, int M, int N, int K) {
  constexpr int NI = TN / 32;              // B frags per wave per kk step
  __shared__ __align__(16) u16 As[128 * 64];
  __shared__ __align__(16) u16 Bs[TN * 64];
  const int tid  = threadIdx.x;
  const int lane = tid & 63;
  const int wid  = tid >> 6;
  // XCD-aware bijective swizzle: consecutive s on one XCD share the N-panel
  const int nwg = gridDim.x;
  const int s = (blockIdx.x & 7) * (nwg >> 3) + (blockIdx.x >> 3);
  const int MT = M >> 7;
  const int tm = (s % MT) * 128, tn = (s / MT) * TN;
  const int wm = (wid >> 1) * 64,  wn = (wid & 1) * (TN / 2);
  const int krow = lane & 15;
  const int ksub = (lane >> 4) * 8;
  f32x4 acc[4][NI] = {};

  for (int kt = 0; kt < K; kt += 64) {
#pragma unroll
    for (int i = 0; i < 4; ++i) {          // A tile: 128x64
      int e = i * 2048 + tid * 8;
      int r = e >> 6;
      int c = (((tid & 7) ^ (r & 7)) << 3); // pre-swizzled source column
      gl_lds16(A + (size_t)(tm + r) * K + kt + c, &As[e]);
    }
#pragma unroll
    for (int i = 0; i < NI; ++i) {         // B tile: TNx64
      int e = i * 2048 + tid * 8;
      int r = e >> 6;
      int c = (((tid & 7) ^ (r & 7)) << 3);
      gl_lds16(Bm + (size_t)(tn + r) * K + kt + c, &Bs[e]);
    }
    __syncthreads();                        // drains vmcnt before ds_read
#pragma unroll
    for (int kk = 0; kk < 64; kk += 32) {
      bf16x8 af[4], bfr[NI];
#pragma unroll
      for (int i = 0; i < 4; ++i) {
        int row = wm + i * 16 + krow;
        int b = (((kk + ksub) >> 3) ^ (row & 7)) << 3;
        af[i] = *reinterpret_cast<const bf16x8*>(&As[row * 64 + b]);
      }
#pragma unroll
      for (int i = 0; i < NI; ++i) {
        int row = wn + i * 16 + krow;
        int b = (((kk + ksub) >> 3) ^ (row & 7)) << 3;
        bfr[i] = *reinterpret_cast<const bf16x8*>(&Bs[row * 64 + b]);
      }
#pragma unroll
      for (int mi = 0; mi < 4; ++mi)
#pragma unroll
        for (int ni = 0; ni < NI; ++ni)
          acc[mi][ni] = __builtin_amdgcn_mfma_f32_16x16x32_bf16(af[mi], bfr[ni], acc[mi][ni], 0, 0, 0);
    }
    __syncthreads();
  }
  // C/D layout (m89-verified): col = lane&15, row = (lane>>4)*4 + j
  const int rb = tm + wm + (lane >> 4) * 4;
  const int cb = tn + wn + (lane & 15);
#pragma unroll
  for (int mi = 0; mi < 4; ++mi)
#pragma unroll
    for (int ni = 0; ni < NI; ++ni)
#pragma unroll
      for (int j = 0; j < 4; ++j) {
        size_t off = (size_t)(rb + mi * 16 + j) * N + cb + ni * 16;
        if constexpr (BF16OUT) ((u16*)Cv)[off] = f2bf(acc[mi][ni][j]);
        else                   ((float*)Cv)[off] = acc[mi][ni][j];
      }
}

// ---------------- fused conv+silu+decay + chunk-local scan (LDS-staged) ----------------
// grid: (b,h,c) = 2*16*32 blocks of 64 threads (one k-channel per lane).
__global__ void scanA_kernel(const u16* __restrict__ proj,
                             const float* __restrict__ conv_w,
                             const float* __restrict__ conv_b,
                             const float* __restrict__ decay,
                             u16* __restrict__ vv,
                             float* __restrict__ ye, float* __restrict__ Pc,
                             float* __restrict__ pfx) {
  __shared__ __align__(16) u16 lv[CHUNK_ * 64];        // v rows t0..t0+63
  __shared__ __align__(16) u16 lk[(CHUNK_ + 8) * 64];  // k rows t0-6..t0+65
  int bh = blockIdx.x >> 5, c = blockIdx.x & 31;
  int b = bh >> 4, h = bh & 15;
  int k = threadIdx.x;                 // 64 lanes
  int d0 = h * 64;
  int t0 = c * CHUNK_;
  int rsub = k >> 3, cblk = (k & 7) * 8;
  // ---- stage v: 8 x 16B per lane ----
#pragma unroll
  for (int it = 0; it < 8; ++it) {
    int r = it * 8 + rsub;
    *reinterpret_cast<u16x8*>(&lv[r * 64 + cblk]) =
      *reinterpret_cast<const u16x8*>(&proj[(size_t)(b * T_ + t0 + r) * NP_ + 1024 + d0 + cblk]);
  }
  // ---- stage k rows t0-6 .. t0+65, zero-guarded ----
#pragma unroll
  for (int it = 0; it < 9; ++it) {
    int r = it * 8 + rsub;
    int tt = t0 + r - 6;
    u16x8 kv = {0, 0, 0, 0, 0, 0, 0, 0};
    if (tt >= 0 && tt < T_)
      kv = *reinterpret_cast<const u16x8*>(&proj[(size_t)(b * T_ + tt) * NP_ + 2048 + d0 + cblk]);
    *reinterpret_cast<u16x8*>(&lk[r * 64 + cblk]) = kv;
  }
  // ---- per-lane decay factor: lane L holds a for t = t0+L ----
  float wv = bf2f(proj[(size_t)(b * T_ + t0 + k) * NP_ + 3072 + h]);
  float gte = 1.f / (1.f + __expf(-(decay[h] + wv)));
  float my_a = __expf(-8.f * (1.f - gte) - 0.1f);
  int d = d0 + k;
  float cw0 = conv_w[d * 4], cw1 = conv_w[d * 4 + 1],
        cw2 = conv_w[d * 4 + 2], cw3 = conv_w[d * 4 + 3];
  float cb = conv_b[d];
  __syncthreads();
  // ---- serial scan from LDS ----
  u16* V = vv + ((size_t)bh * T_ + t0) * 64 + k;
  float k0 = bf2f(lk[0 * 64 + k]), k1 = bf2f(lk[1 * 64 + k]), k2 = bf2f(lk[2 * 64 + k]);
  float y = 0.f, pf = 1.f, my_pf = 1.f;
#pragma unroll
  for (int i = 0; i < CHUNK_; ++i) {
    float k3 = bf2f(lk[(i + 3) * 64 + k]);
    float v  = bf2f(lv[i * 64 + k]);
    float kc = cb;
    kc = fmaf(k0, cw0, kc); kc = fmaf(k1, cw1, kc);
    kc = fmaf(k2, cw2, kc); kc = fmaf(k3, cw3, kc);
    float sil = kc / (1.f + __expf(-kc));
    float g = v * sil * (1.f / 32.f);
    float a = __shfl(my_a, i);
    y = fmaf(a, y, g);                 // y = g + a*y_prev (state stays f32)
    V[(size_t)i * 64] = f2bf(y);       // output rounds to bf16
    pf *= a;
    if (i == k) my_pf = pf;
    k0 = k1; k1 = k2; k2 = k3;
  }
  pfx[(size_t)bh * T_ + t0 + k] = my_pf;
  ye[(size_t)blockIdx.x * 64 + k] = y;
  Pc[(size_t)blockIdx.x * 64 + k] = pf;
}

// ---------------- cross-chunk combine: 32 blocks x 64 threads (one bh/block) ----------------
__global__ void comb_kernel(const float* __restrict__ ye, const float* __restrict__ Pc,
                            float* __restrict__ cin) {
  int bh = blockIdx.x;
  int k = threadIdx.x;
  float s = 0.f;
#pragma unroll 8
  for (int c = 0; c < NCH_; ++c) {
    size_t i = ((size_t)bh * NCH_ + c) * 64 + k;
    cin[i] = s;
    s = ye[i] + Pc[i] * s;
  }
}

// ---------------- phase C: add carry, out = silu(r)*y, GN partials (x8) ----------------
__global__ void applyC_kernel(const u16* __restrict__ vv, const u16* __restrict__ proj,
                              const float* __restrict__ pfx, const float* __restrict__ cin,
                              u16* __restrict__ ob, float* __restrict__ part) {
  int idx8 = blockIdx.x * 256 + threadIdx.x;   // (bh,t,k/8) linear
  int k8 = (idx8 & 7) * 8;
  int t  = (idx8 >> 3) & 2047;
  int bh = idx8 >> 14;                         // 64 blocks per bh
  int b = bh >> 4, h = bh & 15;
  size_t ebase = ((size_t)bh * T_ + t) * 64 + k8;
  size_t cibase = (((size_t)bh * NCH_) + (t >> 6)) * 64 + k8;
  f32x4 ciA = *reinterpret_cast<const f32x4*>(&cin[cibase]);
  f32x4 ciB = *reinterpret_cast<const f32x4*>(&cin[cibase + 4]);
  float px = pfx[(size_t)bh * T_ + t];
  u16x8 yv = *reinterpret_cast<const u16x8*>(&vv[ebase]);
  u16x8 rv = *reinterpret_cast<const u16x8*>(&proj[(size_t)(b * T_ + t) * NP_ + h * 64 + k8]);
  u16x8 ov;
  float s1 = 0.f, s2 = 0.f;
#pragma unroll
  for (int j = 0; j < 8; ++j) {
    float ci = (j < 4) ? ciA[j] : ciB[j - 4];
    float yf = fmaf(px, ci, bf2f(yv[j]));
    float r = bf2f(rv[j]);
    float o = yf * (r / (1.f + __expf(-r)));
    ov[j] = f2bf(o);
    s1 += o; s2 += o * o;
  }
  *reinterpret_cast<u16x8*>(&ob[ebase]) = ov;
  // block reduce sum / sumsq -> contention-free per-block partials
#pragma unroll
  for (int m = 32; m; m >>= 1) { s1 += __shfl_xor(s1, m); s2 += __shfl_xor(s2, m); }
  __shared__ float ps[8];
  int wid = threadIdx.x >> 6, lane = threadIdx.x & 63;
  if (lane == 0) { ps[wid] = s1; ps[4 + wid] = s2; }
  __syncthreads();
  if (threadIdx.x == 0) {
    part[blockIdx.x]          = ps[0] + ps[1] + ps[2] + ps[3];
    part[NBLK_C + blockIdx.x] = ps[4] + ps[5] + ps[6] + ps[7];
  }
}

// ---------------- reduce partials -> sums[bh], sums[32+bh] ----------------
// applyC block b covers bh = b>>6 (64 blocks per bh, contiguous); 1-wave blocks
__global__ void reduce_kernel(const float* __restrict__ part, float* __restrict__ sums) {
  int bh = blockIdx.x;                         // 32 blocks, 64 threads
  int t = threadIdx.x;
  int base = bh * 64;
  float s1 = part[base + t];
  float s2 = part[NBLK_C + base + t];
#pragma unroll
  for (int m = 32; m; m >>= 1) { s1 += __shfl_xor(s1, m); s2 += __shfl_xor(s2, m); }
  if (t == 0) { sums[bh] = s1; sums[32 + bh] = s2; }
}

// ---------------- phase D: normalize + bf16 cast to (b,t,d) (x8) ----------------
__global__ void applyD_kernel(const u16* __restrict__ ob, const float* __restrict__ sums,
                              const float* __restrict__ gn_w, const float* __restrict__ gn_b,
                              u16* __restrict__ on) {
  int idx8 = blockIdx.x * 256 + threadIdx.x;   // (bh,t,k/8) linear
  int k8 = (idx8 & 7) * 8;
  int t  = (idx8 >> 3) & 2047;
  int bh = idx8 >> 14;
  int b = bh >> 4, h = bh & 15;
  float mean = sums[bh] * GN_INV;
  float var  = sums[32 + bh] * GN_INV - mean * mean;
  float inv  = rsqrtf(var + 1e-5f);
  int d = h * 64 + k8;
  u16x8 o = *reinterpret_cast<const u16x8*>(&ob[((size_t)bh * T_ + t) * 64 + k8]);
  f32x4 gwA = *reinterpret_cast<const f32x4*>(&gn_w[d]);
  f32x4 gwB = *reinterpret_cast<const f32x4*>(&gn_w[d + 4]);
  f32x4 gbA = *reinterpret_cast<const f32x4*>(&gn_b[d]);
  f32x4 gbB = *reinterpret_cast<const f32x4*>(&gn_b[d + 4]);
  u16x8 r;
#pragma unroll
  for (int j = 0; j < 8; ++j) {
    float gw = (j < 4) ? gwA[j] : gwB[j - 4];
    float gb = (j < 4) ? gbA[j] : gbB[j - 4];
    r[j] = f2bf((bf2f(o[j]) - mean) * inv * gw + gb);
  }
  *reinterpret_cast<u16x8*>(&on[(size_t)(b * T_ + t) * D_ + d]) = r;
}

// ---------------- launch ----------------
extern "C" void kernel_launch(void* const* d_in, const int* in_sizes, int n_in,
                              void* d_out, int out_size, void* d_ws, size_t ws_size,
                              hipStream_t stream) {
  const float* x      = (const float*)d_in[0];
  const float* W_in   = (const float*)d_in[1];
  const float* conv_w = (const float*)d_in[2];
  const float* conv_b = (const float*)d_in[3];
  const float* decay  = (const float*)d_in[4];
  const float* gn_w   = (const float*)d_in[5];
  const float* gn_b   = (const float*)d_in[6];
  const float* W_out  = (const float*)d_in[7];

  char* p = (char*)d_ws;
  auto alloc = [&](size_t bytes) { void* r = (void*)p; p += (bytes + 255) & ~(size_t)255; return r; };
  u16*  xb   = (u16*)alloc((size_t)BT_ * D_ * 2);   // also reused as `on` after GEMM1
  u16*  wb   = (u16*)alloc((size_t)NP_ * D_ * 2);
  u16*  wob  = (u16*)alloc((size_t)D_ * D_ * 2);
  u16*  proj = (u16*)alloc((size_t)BT_ * NP_ * 2);  // bf16 proj
  u16*  vv   = (u16*)alloc((size_t)BT_ * D_ * 2);   // bf16 scan output
  u16*  ob   = (u16*)alloc((size_t)BT_ * D_ * 2);   // bf16 gated output
  float* pfx  = (float*)alloc((size_t)B_ * H_ * T_ * 4);
  float* ye   = (float*)alloc((size_t)B_ * H_ * NCH_ * 64 * 4);
  float* Pc   = (float*)alloc((size_t)B_ * H_ * NCH_ * 64 * 4);
  float* cin  = (float*)alloc((size_t)B_ * H_ * NCH_ * 64 * 4);
  float* part = (float*)alloc((size_t)2 * NBLK_C * 4);   // per-block GN partials
  float* sums = (float*)alloc(64 * 4);
  u16*  on   = xb;   // alias: xb dead after GEMM1, on written in applyD

  // Fail-loud guard: if workspace is too small, do nothing (clean absmax
  // failure with valid timing) instead of corrupting memory / crashing.
  if ((size_t)(p - (char*)d_ws) > ws_size) return;

  const int nq = (BT_ * D_ + NP_ * D_ + D_ * D_) / 4;   // fused cvt quads
  hipLaunchKernelGGL(cvt_all, dim3((nq + 255) / 256), dim3(256), 0, stream,
                     x, W_in, W_out, xb, wb, wob);
  hipLaunchKernelGGL((gemm_bt<true, 128>), dim3((NP_ / 128) * (BT_ / 128)), dim3(256), 0, stream,
                     xb, wb, (void*)proj, BT_, NP_, D_);
  hipLaunchKernelGGL(scanA_kernel,  dim3(B_ * H_ * NCH_), dim3(64),  0, stream,
                     proj, conv_w, conv_b, decay, vv, ye, Pc, pfx);
  hipLaunchKernelGGL(comb_kernel,   dim3(32),             dim3(64),  0, stream, ye, Pc, cin);
  hipLaunchKernelGGL(applyC_kernel, dim3(NBLK_C),         dim3(256), 0, stream, vv, proj, pfx, cin, ob, part);
  hipLaunchKernelGGL(reduce_kernel, dim3(32),             dim3(64),  0, stream, part, sums);
  hipLaunchKernelGGL(applyD_kernel, dim3(BT_ * D_ / 2048), dim3(256), 0, stream, ob, sums, gn_w, gn_b, on);
  hipLaunchKernelGGL((gemm_bt<false, 64>), dim3((D_ / 64) * (BT_ / 128)), dim3(256), 0, stream,
                     on, wob, d_out, BT_, D_, D_);
}